// Round 9
// baseline (352.429 us; speedup 1.0000x reference)
//
#include <hip/hip_runtime.h>
#include <hip/hip_bf16.h>

// Problem constants (fixed by the reference): B=16, V=8192, N=2048, H=128, C_OUT=7
#define B_GR   16
#define V_PTS  8192
#define N_RES  2048
#define H_DIM  128
#define C_OUT  7
#define SEGS   16            // pool kernel: residue segments per graph (128 residues each)
#define NB     512           // x-buckets for pruned search
#define CPAD   520           // padded per-graph cellstart stride
#define BW     0.203125f     // bucket width = 104/512 (exact: 13/64)
#define MARG   0.5f          // exclusion margin >> ~1.5e-3 fp cancellation error
#define EPAD   0.01f         // bucket-edge pad >> ~1e-5 bucketof rounding

// Ledger: r1 pk-f32 not double-rate; r2 issue-bound; r3 atomics free; r4/r5
// per-n amortization + LDS pipelining nil (brute argmin ~59 µs = VALU ceiling).
// r6 pruned+per-lane: 241 µs, 1.25e7 bank conflicts. r7 wave-union+broadcast:
// conflicts ~0 but STILL 208 µs -> ~1900 cands/wave from weak-seed fixed-W.
// r8: expanding-ring scan with incremental tightening (this kernel) — bench
// infra failed twice, no data; resubmitted verbatim (+bidx=0 hardening).

// exact bucket function (identical in prep & search)
__device__ __forceinline__ int bucketof(float x) {
    int bk = (int)floorf((x + 52.0f) * (512.0f / 104.0f));
    return bk < 0 ? 0 : (bk > NB - 1 ? NB - 1 : bk);
}
__device__ __forceinline__ float lo_edge(int k) {      // exact: k*(13/64)-52
    return (float)k * BW - 52.0f;
}

// one candidate: bit-exact reference sequence + lexicographic (d, orig idx)
__device__ __forceinline__ void eval_one(const float4 c, int id,
                                         float vx, float vy, float vz, float vsq,
                                         float& best, int& bidx) {
    float dot = __fadd_rn(__fadd_rn(__fmul_rn(vx, c.x), __fmul_rn(vy, c.y)),
                          __fmul_rn(vz, c.z));
    float d = __fadd_rn(fmaf(-2.0f, dot, vsq), c.w);
    bool take = (d < best) || ((d == best) && (id < bidx));
    best = take ? d : best;
    bidx = take ? id : bidx;
}

// ---------------------------------------------------------------------------
// Kernel 0 (prep): per graph — counting-sort RESIDUES by x-bucket into
// (float4 x,y,z,csq + orig idx u32) + exclusive bucket starts; counting-sort
// VERTICES by x-bucket into float4 (x,y,z,vsq); zero the hit mask. All
// squared-norms use the exact reference fp sequence. Within-bucket order is
// arbitrary — harmless, selection is lexicographic. 16 blocks x 256 threads.
// ---------------------------------------------------------------------------
__global__ __launch_bounds__(256) void k_prep(const float* __restrict__ coords,
                                              const float* __restrict__ verts,
                                              float4* __restrict__ sf4g,
                                              unsigned int* __restrict__ sidxg,
                                              unsigned int* __restrict__ cellsg,
                                              float4* __restrict__ vf4g,
                                              float* __restrict__ msk) {
    __shared__ unsigned int hist[NB];
    __shared__ unsigned int sA[NB], sB[NB];
    __shared__ unsigned int cursor[NB];
    const int b = blockIdx.x;
    const int tid = threadIdx.x;

    // ---- residues ----
    for (int i = tid; i < NB; i += 256) hist[i] = 0;
    for (int i = tid; i < N_RES; i += 256) msk[b * N_RES + i] = 0.0f;
    __syncthreads();

    const float* cb = coords + (size_t)b * N_RES * 3;
    for (int i = tid; i < N_RES; i += 256)
        atomicAdd(&hist[bucketof(cb[i * 3])], 1u);
    __syncthreads();

    for (int i = tid; i < NB; i += 256) sA[i] = hist[i];
    __syncthreads();
    unsigned int* src = sA;
    unsigned int* dst = sB;
    for (int off = 1; off < NB; off <<= 1) {            // Hillis-Steele inclusive
        for (int i = tid; i < NB; i += 256)
            dst[i] = src[i] + (i >= off ? src[i - off] : 0u);
        __syncthreads();
        unsigned int* t = src; src = dst; dst = t;
    }
    for (int i = tid; i < NB; i += 256) {
        unsigned int ex = src[i] - hist[i];             // exclusive start
        cellsg[b * CPAD + i] = ex;
        cursor[i] = ex;
    }
    if (tid == 0) cellsg[b * CPAD + NB] = N_RES;
    __syncthreads();

    for (int i = tid; i < N_RES; i += 256) {
        float x = cb[i * 3 + 0];
        float y = cb[i * 3 + 1];
        float z = cb[i * 3 + 2];
        float csq = __fadd_rn(__fadd_rn(__fmul_rn(x, x), __fmul_rn(y, y)), __fmul_rn(z, z));
        unsigned int pos = atomicAdd(&cursor[bucketof(x)], 1u);
        sf4g[(size_t)b * N_RES + pos] = make_float4(x, y, z, csq);
        sidxg[(size_t)b * N_RES + pos] = (unsigned int)i;
    }
    __syncthreads();

    // ---- vertices (reuse hist/scan/cursor) ----
    for (int i = tid; i < NB; i += 256) hist[i] = 0;
    __syncthreads();
    const float* vb = verts + (size_t)b * V_PTS * 3;
    for (int i = tid; i < V_PTS; i += 256)
        atomicAdd(&hist[bucketof(vb[i * 3])], 1u);
    __syncthreads();
    for (int i = tid; i < NB; i += 256) sA[i] = hist[i];
    __syncthreads();
    src = sA; dst = sB;
    for (int off = 1; off < NB; off <<= 1) {
        for (int i = tid; i < NB; i += 256)
            dst[i] = src[i] + (i >= off ? src[i - off] : 0u);
        __syncthreads();
        unsigned int* t = src; src = dst; dst = t;
    }
    for (int i = tid; i < NB; i += 256)
        cursor[i] = src[i] - hist[i];
    __syncthreads();
    for (int i = tid; i < V_PTS; i += 256) {
        float x = vb[i * 3 + 0];
        float y = vb[i * 3 + 1];
        float z = vb[i * 3 + 2];
        float vsq = __fadd_rn(__fadd_rn(__fmul_rn(x, x), __fmul_rn(y, y)), __fmul_rn(z, z));
        unsigned int pos = atomicAdd(&cursor[bucketof(x)], 1u);
        vf4g[(size_t)b * V_PTS + pos] = make_float4(x, y, z, vsq);
    }
}

// ---------------------------------------------------------------------------
// Kernel 1 (search): one thread per SORTED vertex (lanes adjacent in x).
// Residues staged bucket-sorted in LDS. Expanding-ring scan from the wave's
// center bucket k0: scan bucket k0, then k0+t / k0-t, tightening per-lane
// `best` as we go. A side is done for a lane when the nearest possible x of
// any unscanned bucket on that side is provably too far:
//   right: dxr = lo(kr+1)-EPAD - vx > 0  &&  dxr^2 > best + MARG
//   left : dxl = vx - (lo(kl)+EPAD) > 0  &&  dxl^2 > best + MARG
// (unevaluated r has computed d' >= dx^2 - ~1.5e-3 > best, so no winner or
// exact tie is ever excluded; evaluated candidates use the bit-exact
// sequence + lexicographic (d, orig idx) — validated r6/r7, absmax 0.)
// All reads broadcast (uniform j), loop bounds in SGPRs, ballot termination.
// No lane can terminate before evaluating >=1 candidate (best=FLT_MAX makes
// the done-predicates false), so bidx is always a valid residue index.
// 512 blocks x 256 threads (4 independent waves per block).
// ---------------------------------------------------------------------------
__global__ __launch_bounds__(256) void k_search(const float4* __restrict__ vf4g,
                                                const float4* __restrict__ sf4g,
                                                const unsigned int* __restrict__ sidxg,
                                                const unsigned int* __restrict__ cellsg,
                                                float* __restrict__ msk) {
    __shared__ float4 sf4[N_RES];                       // 32 KB
    __shared__ unsigned short sidx[N_RES];              // 4 KB
    __shared__ unsigned short cs[NB + 1];               // ~1 KB
    const int b     = blockIdx.x >> 5;                  // 32 blocks per graph
    const int chunk = blockIdx.x & 31;

    for (int i = threadIdx.x; i < N_RES; i += 256) {
        sf4[i]  = sf4g[(size_t)b * N_RES + i];
        sidx[i] = (unsigned short)sidxg[(size_t)b * N_RES + i];
    }
    for (int i = threadIdx.x; i < NB + 1; i += 256)
        cs[i] = (unsigned short)cellsg[b * CPAD + i];
    __syncthreads();

    const float4 vv = vf4g[(size_t)b * V_PTS + chunk * 256 + threadIdx.x];
    const float vx = vv.x, vy = vv.y, vz = vv.z, vsq = vv.w;

    float best = 3.402823466e+38f;
    int bidx = 0;                                       // always overwritten

    // wave-uniform center bucket from lane 0's vx (lanes adjacent in x)
    const int k0 = bucketof(__uint_as_float(
                       __builtin_amdgcn_readfirstlane(__float_as_uint(vx))));

    // scan center bucket
    {
        const int j0 = __builtin_amdgcn_readfirstlane((int)cs[k0]);
        const int j1 = __builtin_amdgcn_readfirstlane((int)cs[k0 + 1]);
#pragma unroll 4
        for (int j = j0; j < j1; ++j)
            eval_one(sf4[j], (int)sidx[j], vx, vy, vz, vsq, best, bidx);
    }

    bool rdone = (k0 + 1 >= NB);
    bool ldone = (k0 == 0);

#pragma unroll 1
    for (int t = 1; t < NB; ++t) {
        if (__any(!rdone)) {
            const int kr = k0 + t;
            if (kr < NB) {
                const int j0 = __builtin_amdgcn_readfirstlane((int)cs[kr]);
                const int j1 = __builtin_amdgcn_readfirstlane((int)cs[kr + 1]);
#pragma unroll 4
                for (int j = j0; j < j1; ++j)
                    eval_one(sf4[j], (int)sidx[j], vx, vy, vz, vsq, best, bidx);
                const float dxr = (lo_edge(kr + 1) - EPAD) - vx;
                rdone = (kr + 1 >= NB) ||
                        ((dxr > 0.0f) && (dxr * dxr > best + MARG));
            } else {
                rdone = true;
            }
        }
        if (__any(!ldone)) {
            const int kl = k0 - t;
            if (kl >= 0) {
                const int j0 = __builtin_amdgcn_readfirstlane((int)cs[kl]);
                const int j1 = __builtin_amdgcn_readfirstlane((int)cs[kl + 1]);
#pragma unroll 4
                for (int j = j0; j < j1; ++j)
                    eval_one(sf4[j], (int)sidx[j], vx, vy, vz, vsq, best, bidx);
                const float dxl = vx - (lo_edge(kl) + EPAD);
                ldone = (kl == 0) ||
                        ((dxl > 0.0f) && (dxl * dxl > best + MARG));
            } else {
                ldone = true;
            }
        }
        if (__all(rdone) && __all(ldone)) break;
    }

    msk[b * N_RES + bidx] = 1.0f;                       // orig residue index
}

// ---------------------------------------------------------------------------
// Kernel 2: masked-sum a 128-residue slice of feats with float4 loads; mask
// slice staged from the tiny global msk array. B*SEGS = 256 blocks.
// ---------------------------------------------------------------------------
__global__ __launch_bounds__(256) void k_pool_m(const float* __restrict__ msk,
                                                const float* __restrict__ feats,
                                                float* __restrict__ partial) {
    __shared__ float sm[N_RES / SEGS];                  // 512 B mask slice
    __shared__ float4 red[8][32];
    const int b   = blockIdx.x >> 4;
    const int seg = blockIdx.x & (SEGS - 1);
    const int n0  = seg * (N_RES / SEGS);

    if (threadIdx.x < N_RES / SEGS) sm[threadIdx.x] = msk[b * N_RES + n0 + threadIdx.x];
    __syncthreads();

    const int q = threadIdx.x & 31;                     // float4 column (h = 4q..4q+3)
    const int s = threadIdx.x >> 5;                     // n-slice 0..7
    const float4* fb4 = (const float4*)(feats + ((size_t)b * N_RES + n0) * H_DIM);

    float4 acc = make_float4(0.f, 0.f, 0.f, 0.f);
#pragma unroll
    for (int n = 0; n < N_RES / SEGS / 8; ++n) {
        const int nn = s + n * 8;
        const float m = sm[nn];
        const float4 f = fb4[(size_t)nn * 32 + q];
        acc.x = fmaf(f.x, m, acc.x);
        acc.y = fmaf(f.y, m, acc.y);
        acc.z = fmaf(f.z, m, acc.z);
        acc.w = fmaf(f.w, m, acc.w);
    }
    red[s][q] = acc;
    __syncthreads();

    if (s == 0) {
        float4 t = acc;
#pragma unroll
        for (int i = 1; i < 8; ++i) {
            t.x += red[i][q].x; t.y += red[i][q].y;
            t.z += red[i][q].z; t.w += red[i][q].w;
        }
        ((float4*)partial)[((size_t)b * SEGS + seg) * 32 + q] = t;
    }
}

// ---------------------------------------------------------------------------
// Fallback path (small workspace): brute-force atomicMin kernels (r0).
// ---------------------------------------------------------------------------
#define NSPLIT 16
#define NL     (N_RES / NSPLIT)
#define FVPT   8
#define FVBLK  (256 * FVPT)
#define FVBLKS (V_PTS / FVBLK)
__global__ __launch_bounds__(256, 4) void k_argmin_at(const float* __restrict__ verts,
                                                      const float* __restrict__ coords,
                                                      unsigned long long* __restrict__ mi64) {
    __shared__ float4 sc[NL];
    const int b  = blockIdx.x / (FVBLKS * NSPLIT);
    const int r  = blockIdx.x % (FVBLKS * NSPLIT);
    const int vb = r / NSPLIT;
    const int ns = r % NSPLIT;

    const float* cbase = coords + ((size_t)b * N_RES + ns * NL) * 3;
    if (threadIdx.x < NL) {
        const int i = threadIdx.x;
        float x = cbase[i * 3 + 0];
        float y = cbase[i * 3 + 1];
        float z = cbase[i * 3 + 2];
        float csq = __fadd_rn(__fadd_rn(__fmul_rn(x, x), __fmul_rn(y, y)), __fmul_rn(z, z));
        sc[i] = make_float4(x, y, z, csq);
    }
    __syncthreads();

    const int vbase = vb * FVBLK + threadIdx.x;
    const float* vp = verts + (size_t)b * V_PTS * 3;

    float vx[FVPT], vy[FVPT], vz[FVPT], vsq[FVPT], best[FVPT];
    int bi[FVPT];
#pragma unroll
    for (int k = 0; k < FVPT; ++k) {
        const int v = vbase + k * 256;
        vx[k] = vp[v * 3 + 0];
        vy[k] = vp[v * 3 + 1];
        vz[k] = vp[v * 3 + 2];
        vsq[k] = __fadd_rn(__fadd_rn(__fmul_rn(vx[k], vx[k]), __fmul_rn(vy[k], vy[k])),
                           __fmul_rn(vz[k], vz[k]));
        best[k] = 3.402823466e+38f;
        bi[k] = 0;
    }
#pragma unroll 2
    for (int n = 0; n < NL; ++n) {
        const float4 c = sc[n];
#pragma unroll
        for (int k = 0; k < FVPT; ++k) {
            float dot = __fadd_rn(__fadd_rn(__fmul_rn(vx[k], c.x), __fmul_rn(vy[k], c.y)),
                                  __fmul_rn(vz[k], c.z));
            float d = __fadd_rn(fmaf(-2.0f, dot, vsq[k]), c.w);
            bool m = d < best[k];
            best[k] = m ? d : best[k];
            bi[k]   = m ? n : bi[k];
        }
    }
#pragma unroll
    for (int k = 0; k < FVPT; ++k) {
        unsigned int bits = __float_as_uint(best[k]);
        unsigned int key  = bits ^ (unsigned int)(((int)bits >> 31) | 0x80000000);
        unsigned long long packed =
            ((unsigned long long)key << 32) | (unsigned int)(ns * NL + bi[k]);
        atomicMin(&mi64[(size_t)b * V_PTS + vbase + k * 256], packed);
    }
}

__global__ __launch_bounds__(256) void k_pool_at(const unsigned long long* __restrict__ mi64,
                                                 const float* __restrict__ feats,
                                                 float* __restrict__ partial) {
    __shared__ float msk[N_RES];
    __shared__ float4 red[8][32];
    const int b   = blockIdx.x >> 4;
    const int seg = blockIdx.x & (SEGS - 1);

    for (int i = threadIdx.x; i < N_RES; i += 256) msk[i] = 0.0f;
    __syncthreads();
    const unsigned long long* mb = mi64 + (size_t)b * V_PTS;
    for (int v = threadIdx.x; v < V_PTS; v += 256)
        msk[(unsigned int)mb[v]] = 1.0f;
    __syncthreads();

    const int q = threadIdx.x & 31;
    const int s = threadIdx.x >> 5;
    const int n0 = seg * (N_RES / SEGS);
    const float4* fb4 = (const float4*)(feats + ((size_t)b * N_RES + n0) * H_DIM);

    float4 acc = make_float4(0.f, 0.f, 0.f, 0.f);
#pragma unroll
    for (int n = 0; n < N_RES / SEGS / 8; ++n) {
        const int nn = s + n * 8;
        const float m = msk[n0 + nn];
        const float4 f = fb4[(size_t)nn * 32 + q];
        acc.x = fmaf(f.x, m, acc.x);
        acc.y = fmaf(f.y, m, acc.y);
        acc.z = fmaf(f.z, m, acc.z);
        acc.w = fmaf(f.w, m, acc.w);
    }
    red[s][q] = acc;
    __syncthreads();
    if (s == 0) {
        float4 t = acc;
#pragma unroll
        for (int i = 1; i < 8; ++i) {
            t.x += red[i][q].x; t.y += red[i][q].y;
            t.z += red[i][q].z; t.w += red[i][q].w;
        }
        ((float4*)partial)[((size_t)b * SEGS + seg) * 32 + q] = t;
    }
}

// ---------------------------------------------------------------------------
// Kernel 3: per-graph block — reduce 16 seg partials -> pooled[H], then
// relu(pooled@W1+b1)@W2+b2 -> out[b][7]. 16 blocks x 128 threads.
// (r1 lesson: last-block-done fusion costs ~19 µs via device-scope
// threadfence on non-coherent XCD L2s. Separate tiny launch is cheaper.)
// ---------------------------------------------------------------------------
__global__ __launch_bounds__(128) void k_mlp(const float* __restrict__ partial,
                                             const float* __restrict__ W1,
                                             const float* __restrict__ b1,
                                             const float* __restrict__ W2,
                                             const float* __restrict__ b2,
                                             float* __restrict__ out) {
    __shared__ float pooled[H_DIM];
    __shared__ float h1[H_DIM];
    const int b = blockIdx.x;
    const int j = threadIdx.x;

    float s = 0.0f;
#pragma unroll
    for (int g = 0; g < SEGS; ++g)
        s += partial[((size_t)b * SEGS + g) * H_DIM + j];
    pooled[j] = s;
    __syncthreads();

    float acc = b1[j];
#pragma unroll 8
    for (int hh = 0; hh < H_DIM; ++hh)
        acc = fmaf(pooled[hh], W1[hh * H_DIM + j], acc);
    h1[j] = fmaxf(acc, 0.0f);
    __syncthreads();

    if (j < C_OUT) {
        float o = b2[j];
#pragma unroll 8
        for (int hh = 0; hh < H_DIM; ++hh)
            o = fmaf(h1[hh], W2[hh * C_OUT + j], o);
        out[(size_t)b * C_OUT + j] = o;
    }
}

extern "C" void kernel_launch(void* const* d_in, const int* in_sizes, int n_in,
                              void* d_out, int out_size, void* d_ws, size_t ws_size,
                              hipStream_t stream) {
    const float* verts  = (const float*)d_in[0];   // [B,V,3]
    const float* coords = (const float*)d_in[1];   // [B,N,3]
    const float* feats  = (const float*)d_in[2];   // [B,N,H]
    const float* W1     = (const float*)d_in[3];   // [H,H]
    const float* b1     = (const float*)d_in[4];   // [H]
    const float* W2     = (const float*)d_in[5];   // [H,C_OUT]
    const float* b2     = (const float*)d_in[6];   // [C_OUT]
    float* out = (float*)d_out;                    // [B,C_OUT]

    // workspace layout (pruned path, ~2.9 MB total)
    const size_t vf4_bytes  = (size_t)B_GR * V_PTS * 16;   // 2 MB (16B aligned @0)
    const size_t sf4_bytes  = (size_t)B_GR * N_RES * 16;   // 512 KB
    const size_t sidx_bytes = (size_t)B_GR * N_RES * 4;    // 128 KB
    const size_t cell_bytes = (size_t)B_GR * CPAD * 4;     // ~33 KB
    const size_t msk_bytes  = (size_t)B_GR * N_RES * 4;    // 128 KB
    const size_t pp_bytes   = (size_t)B_GR * SEGS * H_DIM * 4; // 128 KB
    const size_t need = vf4_bytes + sf4_bytes + sidx_bytes + cell_bytes + msk_bytes + pp_bytes;

    if (ws_size >= need) {
        char* p = (char*)d_ws;
        float4*       vf4g  = (float4*)p;                      p += vf4_bytes;
        float4*       sf4g  = (float4*)p;                      p += sf4_bytes;
        unsigned int* sidxg = (unsigned int*)p;                p += sidx_bytes;
        unsigned int* cells = (unsigned int*)p;                p += cell_bytes;
        float*        msk   = (float*)p;                       p += msk_bytes;
        float*        partial = (float*)p;

        k_prep  <<<B_GR,               256, 0, stream>>>(coords, verts, sf4g, sidxg,
                                                         cells, vf4g, msk);
        k_search<<<B_GR * V_PTS / 256, 256, 0, stream>>>(vf4g, sf4g, sidxg, cells, msk);
        k_pool_m<<<B_GR * SEGS,        256, 0, stream>>>(msk, feats, partial);
        k_mlp   <<<B_GR,               128, 0, stream>>>(partial, W1, b1, W2, b2, out);
    } else {
        // ---- fallback: brute-force atomicMin path ----
        unsigned long long* mi64 = (unsigned long long*)d_ws;              // 1 MB
        float* partial = (float*)((char*)d_ws + (size_t)B_GR * V_PTS * 8); // 128 KB

        hipMemsetAsync(mi64, 0xFF, (size_t)B_GR * V_PTS * 8, stream);
        k_argmin_at<<<B_GR * FVBLKS * NSPLIT, 256, 0, stream>>>(verts, coords, mi64);
        k_pool_at  <<<B_GR * SEGS,            256, 0, stream>>>(mi64, feats, partial);
        k_mlp      <<<B_GR,                   128, 0, stream>>>(partial, W1, b1, W2, b2, out);
    }
}

// Round 10
// 301.825 us; speedup vs baseline: 1.1677x; 1.1677x over previous
//
#include <hip/hip_runtime.h>
#include <hip/hip_bf16.h>

// Problem constants (fixed by the reference): B=16, V=8192, N=2048, H=128, C_OUT=7
#define B_GR   16
#define V_PTS  8192
#define N_RES  2048
#define H_DIM  128
#define C_OUT  7
#define SEGS   16            // pool kernel: residue segments per graph (128 residues each)
#define NB     128           // x-buckets (coarse: ~16 residues avg, ~66 at center)
#define CPAD   136           // padded per-graph cellstart stride
#define BW     0.8125f       // bucket width = 104/128 (exact: 13/16)

// Ledger: r1 pk-f32 not double-rate; r2 issue-bound; r3 atomics free; r4/r5
// micro-opts nil (brute argmin ~59 µs = VALU ceiling, best total 144.6).
// r6 per-lane scatter: 241 µs (1.25e7 bank conflicts -> broadcast mandatory).
// r7 weak-seed fixed-W: 208 µs (~1900 cands/wave, slab inflated 4x).
// r9 fine-ring ballots: 242 µs @ VALUBusy 14% (eval count halved but serial
// per-bucket overhead dominates). r10: two-phase, 3 long uniform loops —
// strong seed (own-bucket +-1 via wave-union, coarse NB=128) then validated
// W-slab with union bounds. No ballots in hot path.

// exact bucket function (identical in prep & search)
__device__ __forceinline__ int bucketof(float x) {
    int bk = (int)floorf((x + 52.0f) * (128.0f / 104.0f));
    return bk < 0 ? 0 : (bk > NB - 1 ? NB - 1 : bk);
}

// one candidate: bit-exact reference sequence + lexicographic (d, orig idx)
__device__ __forceinline__ void eval_one(const float4 c, int id,
                                         float vx, float vy, float vz, float vsq,
                                         float& best, int& bidx) {
    float dot = __fadd_rn(__fadd_rn(__fmul_rn(vx, c.x), __fmul_rn(vy, c.y)),
                          __fmul_rn(vz, c.z));
    float d = __fadd_rn(fmaf(-2.0f, dot, vsq), c.w);
    bool take = (d < best) || ((d == best) && (id < bidx));
    best = take ? d : best;
    bidx = take ? id : bidx;
}

__device__ __forceinline__ int wave_imin(int v) {
#pragma unroll
    for (int o = 1; o < 64; o <<= 1) { int t = __shfl_xor(v, o); v = t < v ? t : v; }
    return __builtin_amdgcn_readfirstlane(v);
}
__device__ __forceinline__ int wave_imax(int v) {
#pragma unroll
    for (int o = 1; o < 64; o <<= 1) { int t = __shfl_xor(v, o); v = t > v ? t : v; }
    return __builtin_amdgcn_readfirstlane(v);
}

// ---------------------------------------------------------------------------
// Kernel 0 (prep): per graph — counting-sort RESIDUES by x-bucket into
// (float4 x,y,z,csq + orig idx u32) + exclusive bucket starts; counting-sort
// VERTICES by x-bucket into float4 (x,y,z,vsq); zero the hit mask. All
// squared-norms use the exact reference fp sequence. Within-bucket order is
// arbitrary — harmless, selection is lexicographic. 16 blocks x 256 threads.
// ---------------------------------------------------------------------------
__global__ __launch_bounds__(256) void k_prep(const float* __restrict__ coords,
                                              const float* __restrict__ verts,
                                              float4* __restrict__ sf4g,
                                              unsigned int* __restrict__ sidxg,
                                              unsigned int* __restrict__ cellsg,
                                              float4* __restrict__ vf4g,
                                              float* __restrict__ msk) {
    __shared__ unsigned int hist[NB];
    __shared__ unsigned int sA[NB], sB[NB];
    __shared__ unsigned int cursor[NB];
    const int b = blockIdx.x;
    const int tid = threadIdx.x;

    // ---- residues ----
    for (int i = tid; i < NB; i += 256) hist[i] = 0;
    for (int i = tid; i < N_RES; i += 256) msk[b * N_RES + i] = 0.0f;
    __syncthreads();

    const float* cb = coords + (size_t)b * N_RES * 3;
    for (int i = tid; i < N_RES; i += 256)
        atomicAdd(&hist[bucketof(cb[i * 3])], 1u);
    __syncthreads();

    for (int i = tid; i < NB; i += 256) sA[i] = hist[i];
    __syncthreads();
    unsigned int* src = sA;
    unsigned int* dst = sB;
    for (int off = 1; off < NB; off <<= 1) {            // Hillis-Steele inclusive
        for (int i = tid; i < NB; i += 256)
            dst[i] = src[i] + (i >= off ? src[i - off] : 0u);
        __syncthreads();
        unsigned int* t = src; src = dst; dst = t;
    }
    for (int i = tid; i < NB; i += 256) {
        unsigned int ex = src[i] - hist[i];             // exclusive start
        cellsg[b * CPAD + i] = ex;
        cursor[i] = ex;
    }
    if (tid == 0) cellsg[b * CPAD + NB] = N_RES;
    __syncthreads();

    for (int i = tid; i < N_RES; i += 256) {
        float x = cb[i * 3 + 0];
        float y = cb[i * 3 + 1];
        float z = cb[i * 3 + 2];
        float csq = __fadd_rn(__fadd_rn(__fmul_rn(x, x), __fmul_rn(y, y)), __fmul_rn(z, z));
        unsigned int pos = atomicAdd(&cursor[bucketof(x)], 1u);
        sf4g[(size_t)b * N_RES + pos] = make_float4(x, y, z, csq);
        sidxg[(size_t)b * N_RES + pos] = (unsigned int)i;
    }
    __syncthreads();

    // ---- vertices (reuse hist/scan/cursor) ----
    for (int i = tid; i < NB; i += 256) hist[i] = 0;
    __syncthreads();
    const float* vb = verts + (size_t)b * V_PTS * 3;
    for (int i = tid; i < V_PTS; i += 256)
        atomicAdd(&hist[bucketof(vb[i * 3])], 1u);
    __syncthreads();
    for (int i = tid; i < NB; i += 256) sA[i] = hist[i];
    __syncthreads();
    src = sA; dst = sB;
    for (int off = 1; off < NB; off <<= 1) {
        for (int i = tid; i < NB; i += 256)
            dst[i] = src[i] + (i >= off ? src[i - off] : 0u);
        __syncthreads();
        unsigned int* t = src; src = dst; dst = t;
    }
    for (int i = tid; i < NB; i += 256)
        cursor[i] = src[i] - hist[i];
    __syncthreads();
    for (int i = tid; i < V_PTS; i += 256) {
        float x = vb[i * 3 + 0];
        float y = vb[i * 3 + 1];
        float z = vb[i * 3 + 2];
        float vsq = __fadd_rn(__fadd_rn(__fmul_rn(x, x), __fmul_rn(y, y)), __fmul_rn(z, z));
        unsigned int pos = atomicAdd(&cursor[bucketof(x)], 1u);
        vf4g[(size_t)b * V_PTS + pos] = make_float4(x, y, z, vsq);
    }
}

// ---------------------------------------------------------------------------
// Kernel 1 (search): one thread per SORTED vertex (lanes adjacent in x).
// Residues staged bucket-sorted in LDS. Exactly 3 wave-uniform loops:
//  seed:  [s0,s1) = wave-union of each lane's own bucket +-1 — contains all
//         residues with |dx| <= 0.81, so per-lane best lands ~= final.
//  slab:  W = sqrt(best+1)+1/16 (absmax-0-validated formula, r7); scan
//         [jlo,s0) and [s1,jhi) with jlo/jhi = wave-union bucket bounds.
// Exclusion safety: an unscanned residue r has x_r below lo-edge of the
// bucket containing vx-W (or mirrored), so |vx-x_r| > W - 4.4e-5 and its
// computed d' >= true - 4e-3 > best + 0.99 — can never win or tie. Every
// evaluated candidate uses the bit-exact sequence + lexicographic (d, idx).
// Empty seed (tail vertex beyond all residues) -> best=FLT_MAX -> W huge ->
// full-range scan: correct, rare. All reads broadcast (uniform j), bounds in
// SGPRs, no ballots. 512 blocks x 256 threads (4 waves/block).
// ---------------------------------------------------------------------------
__global__ __launch_bounds__(256) void k_search(const float4* __restrict__ vf4g,
                                                const float4* __restrict__ sf4g,
                                                const unsigned int* __restrict__ sidxg,
                                                const unsigned int* __restrict__ cellsg,
                                                float* __restrict__ msk) {
    __shared__ float4 sf4[N_RES];                       // 32 KB
    __shared__ unsigned short sidx[N_RES];              // 4 KB
    __shared__ unsigned short cs[NB + 1];               // 258 B
    const int b     = blockIdx.x >> 5;                  // 32 blocks per graph
    const int chunk = blockIdx.x & 31;

    for (int i = threadIdx.x; i < N_RES; i += 256) {
        sf4[i]  = sf4g[(size_t)b * N_RES + i];
        sidx[i] = (unsigned short)sidxg[(size_t)b * N_RES + i];
    }
    for (int i = threadIdx.x; i < NB + 1; i += 256)
        cs[i] = (unsigned short)cellsg[b * CPAD + i];
    __syncthreads();

    const float4 vv = vf4g[(size_t)b * V_PTS + chunk * 256 + threadIdx.x];
    const float vx = vv.x, vy = vv.y, vz = vv.z, vsq = vv.w;

    float best = 3.402823466e+38f;
    int bidx = 0;

    // ---- phase 1: strong seed — wave-union of own bucket +-1 ----
    const int kl = bucketof(vx);                        // per-lane
    const int klo = kl - 1 < 0 ? 0 : kl - 1;
    const int khi = kl + 2 > NB ? NB : kl + 2;
    const int s0 = wave_imin((int)cs[klo]);
    const int s1 = wave_imax((int)cs[khi]);
#pragma unroll 4
    for (int j = s0; j < s1; ++j)
        eval_one(sf4[j], (int)sidx[j], vx, vy, vz, vsq, best, bidx);

    // ---- phase 2: W-slab, skipping the seed range ----
    const float W = sqrtf(best + 1.0f) + 0.0625f;
    const int jlo = wave_imin((int)cs[bucketof(vx - W)]);
    const int jhi = wave_imax((int)cs[bucketof(vx + W) + 1]);
#pragma unroll 4
    for (int j = jlo; j < s0; ++j)
        eval_one(sf4[j], (int)sidx[j], vx, vy, vz, vsq, best, bidx);
#pragma unroll 4
    for (int j = s1; j < jhi; ++j)
        eval_one(sf4[j], (int)sidx[j], vx, vy, vz, vsq, best, bidx);

    msk[b * N_RES + bidx] = 1.0f;                       // orig residue index
}

// ---------------------------------------------------------------------------
// Kernel 2: masked-sum a 128-residue slice of feats with float4 loads; mask
// slice staged from the tiny global msk array. B*SEGS = 256 blocks.
// ---------------------------------------------------------------------------
__global__ __launch_bounds__(256) void k_pool_m(const float* __restrict__ msk,
                                                const float* __restrict__ feats,
                                                float* __restrict__ partial) {
    __shared__ float sm[N_RES / SEGS];                  // 512 B mask slice
    __shared__ float4 red[8][32];
    const int b   = blockIdx.x >> 4;
    const int seg = blockIdx.x & (SEGS - 1);
    const int n0  = seg * (N_RES / SEGS);

    if (threadIdx.x < N_RES / SEGS) sm[threadIdx.x] = msk[b * N_RES + n0 + threadIdx.x];
    __syncthreads();

    const int q = threadIdx.x & 31;                     // float4 column (h = 4q..4q+3)
    const int s = threadIdx.x >> 5;                     // n-slice 0..7
    const float4* fb4 = (const float4*)(feats + ((size_t)b * N_RES + n0) * H_DIM);

    float4 acc = make_float4(0.f, 0.f, 0.f, 0.f);
#pragma unroll
    for (int n = 0; n < N_RES / SEGS / 8; ++n) {
        const int nn = s + n * 8;
        const float m = sm[nn];
        const float4 f = fb4[(size_t)nn * 32 + q];
        acc.x = fmaf(f.x, m, acc.x);
        acc.y = fmaf(f.y, m, acc.y);
        acc.z = fmaf(f.z, m, acc.z);
        acc.w = fmaf(f.w, m, acc.w);
    }
    red[s][q] = acc;
    __syncthreads();

    if (s == 0) {
        float4 t = acc;
#pragma unroll
        for (int i = 1; i < 8; ++i) {
            t.x += red[i][q].x; t.y += red[i][q].y;
            t.z += red[i][q].z; t.w += red[i][q].w;
        }
        ((float4*)partial)[((size_t)b * SEGS + seg) * 32 + q] = t;
    }
}

// ---------------------------------------------------------------------------
// Fallback path (small workspace): brute-force atomicMin kernels (r0).
// ---------------------------------------------------------------------------
#define NSPLIT 16
#define NL     (N_RES / NSPLIT)
#define FVPT   8
#define FVBLK  (256 * FVPT)
#define FVBLKS (V_PTS / FVBLK)
__global__ __launch_bounds__(256, 4) void k_argmin_at(const float* __restrict__ verts,
                                                      const float* __restrict__ coords,
                                                      unsigned long long* __restrict__ mi64) {
    __shared__ float4 sc[NL];
    const int b  = blockIdx.x / (FVBLKS * NSPLIT);
    const int r  = blockIdx.x % (FVBLKS * NSPLIT);
    const int vb = r / NSPLIT;
    const int ns = r % NSPLIT;

    const float* cbase = coords + ((size_t)b * N_RES + ns * NL) * 3;
    if (threadIdx.x < NL) {
        const int i = threadIdx.x;
        float x = cbase[i * 3 + 0];
        float y = cbase[i * 3 + 1];
        float z = cbase[i * 3 + 2];
        float csq = __fadd_rn(__fadd_rn(__fmul_rn(x, x), __fmul_rn(y, y)), __fmul_rn(z, z));
        sc[i] = make_float4(x, y, z, csq);
    }
    __syncthreads();

    const int vbase = vb * FVBLK + threadIdx.x;
    const float* vp = verts + (size_t)b * V_PTS * 3;

    float vx[FVPT], vy[FVPT], vz[FVPT], vsq[FVPT], best[FVPT];
    int bi[FVPT];
#pragma unroll
    for (int k = 0; k < FVPT; ++k) {
        const int v = vbase + k * 256;
        vx[k] = vp[v * 3 + 0];
        vy[k] = vp[v * 3 + 1];
        vz[k] = vp[v * 3 + 2];
        vsq[k] = __fadd_rn(__fadd_rn(__fmul_rn(vx[k], vx[k]), __fmul_rn(vy[k], vy[k])),
                           __fmul_rn(vz[k], vz[k]));
        best[k] = 3.402823466e+38f;
        bi[k] = 0;
    }
#pragma unroll 2
    for (int n = 0; n < NL; ++n) {
        const float4 c = sc[n];
#pragma unroll
        for (int k = 0; k < FVPT; ++k) {
            float dot = __fadd_rn(__fadd_rn(__fmul_rn(vx[k], c.x), __fmul_rn(vy[k], c.y)),
                                  __fmul_rn(vz[k], c.z));
            float d = __fadd_rn(fmaf(-2.0f, dot, vsq[k]), c.w);
            bool m = d < best[k];
            best[k] = m ? d : best[k];
            bi[k]   = m ? n : bi[k];
        }
    }
#pragma unroll
    for (int k = 0; k < FVPT; ++k) {
        unsigned int bits = __float_as_uint(best[k]);
        unsigned int key  = bits ^ (unsigned int)(((int)bits >> 31) | 0x80000000);
        unsigned long long packed =
            ((unsigned long long)key << 32) | (unsigned int)(ns * NL + bi[k]);
        atomicMin(&mi64[(size_t)b * V_PTS + vbase + k * 256], packed);
    }
}

__global__ __launch_bounds__(256) void k_pool_at(const unsigned long long* __restrict__ mi64,
                                                 const float* __restrict__ feats,
                                                 float* __restrict__ partial) {
    __shared__ float msk[N_RES];
    __shared__ float4 red[8][32];
    const int b   = blockIdx.x >> 4;
    const int seg = blockIdx.x & (SEGS - 1);

    for (int i = threadIdx.x; i < N_RES; i += 256) msk[i] = 0.0f;
    __syncthreads();
    const unsigned long long* mb = mi64 + (size_t)b * V_PTS;
    for (int v = threadIdx.x; v < V_PTS; v += 256)
        msk[(unsigned int)mb[v]] = 1.0f;
    __syncthreads();

    const int q = threadIdx.x & 31;
    const int s = threadIdx.x >> 5;
    const int n0 = seg * (N_RES / SEGS);
    const float4* fb4 = (const float4*)(feats + ((size_t)b * N_RES + n0) * H_DIM);

    float4 acc = make_float4(0.f, 0.f, 0.f, 0.f);
#pragma unroll
    for (int n = 0; n < N_RES / SEGS / 8; ++n) {
        const int nn = s + n * 8;
        const float m = msk[n0 + nn];
        const float4 f = fb4[(size_t)nn * 32 + q];
        acc.x = fmaf(f.x, m, acc.x);
        acc.y = fmaf(f.y, m, acc.y);
        acc.z = fmaf(f.z, m, acc.z);
        acc.w = fmaf(f.w, m, acc.w);
    }
    red[s][q] = acc;
    __syncthreads();
    if (s == 0) {
        float4 t = acc;
#pragma unroll
        for (int i = 1; i < 8; ++i) {
            t.x += red[i][q].x; t.y += red[i][q].y;
            t.z += red[i][q].z; t.w += red[i][q].w;
        }
        ((float4*)partial)[((size_t)b * SEGS + seg) * 32 + q] = t;
    }
}

// ---------------------------------------------------------------------------
// Kernel 3: per-graph block — reduce 16 seg partials -> pooled[H], then
// relu(pooled@W1+b1)@W2+b2 -> out[b][7]. 16 blocks x 128 threads.
// ---------------------------------------------------------------------------
__global__ __launch_bounds__(128) void k_mlp(const float* __restrict__ partial,
                                             const float* __restrict__ W1,
                                             const float* __restrict__ b1,
                                             const float* __restrict__ W2,
                                             const float* __restrict__ b2,
                                             float* __restrict__ out) {
    __shared__ float pooled[H_DIM];
    __shared__ float h1[H_DIM];
    const int b = blockIdx.x;
    const int j = threadIdx.x;

    float s = 0.0f;
#pragma unroll
    for (int g = 0; g < SEGS; ++g)
        s += partial[((size_t)b * SEGS + g) * H_DIM + j];
    pooled[j] = s;
    __syncthreads();

    float acc = b1[j];
#pragma unroll 8
    for (int hh = 0; hh < H_DIM; ++hh)
        acc = fmaf(pooled[hh], W1[hh * H_DIM + j], acc);
    h1[j] = fmaxf(acc, 0.0f);
    __syncthreads();

    if (j < C_OUT) {
        float o = b2[j];
#pragma unroll 8
        for (int hh = 0; hh < H_DIM; ++hh)
            o = fmaf(h1[hh], W2[hh * C_OUT + j], o);
        out[(size_t)b * C_OUT + j] = o;
    }
}

extern "C" void kernel_launch(void* const* d_in, const int* in_sizes, int n_in,
                              void* d_out, int out_size, void* d_ws, size_t ws_size,
                              hipStream_t stream) {
    const float* verts  = (const float*)d_in[0];   // [B,V,3]
    const float* coords = (const float*)d_in[1];   // [B,N,3]
    const float* feats  = (const float*)d_in[2];   // [B,N,H]
    const float* W1     = (const float*)d_in[3];   // [H,H]
    const float* b1     = (const float*)d_in[4];   // [H]
    const float* W2     = (const float*)d_in[5];   // [H,C_OUT]
    const float* b2     = (const float*)d_in[6];   // [C_OUT]
    float* out = (float*)d_out;                    // [B,C_OUT]

    // workspace layout (pruned path, ~2.8 MB total)
    const size_t vf4_bytes  = (size_t)B_GR * V_PTS * 16;   // 2 MB (16B aligned @0)
    const size_t sf4_bytes  = (size_t)B_GR * N_RES * 16;   // 512 KB
    const size_t sidx_bytes = (size_t)B_GR * N_RES * 4;    // 128 KB
    const size_t cell_bytes = (size_t)B_GR * CPAD * 4;     // ~8.7 KB
    const size_t msk_bytes  = (size_t)B_GR * N_RES * 4;    // 128 KB
    const size_t pp_bytes   = (size_t)B_GR * SEGS * H_DIM * 4; // 128 KB
    const size_t need = vf4_bytes + sf4_bytes + sidx_bytes + cell_bytes + msk_bytes + pp_bytes;

    if (ws_size >= need) {
        char* p = (char*)d_ws;
        float4*       vf4g  = (float4*)p;                      p += vf4_bytes;
        float4*       sf4g  = (float4*)p;                      p += sf4_bytes;
        unsigned int* sidxg = (unsigned int*)p;                p += sidx_bytes;
        unsigned int* cells = (unsigned int*)p;                p += cell_bytes;
        float*        msk   = (float*)p;                       p += msk_bytes;
        float*        partial = (float*)p;

        k_prep  <<<B_GR,               256, 0, stream>>>(coords, verts, sf4g, sidxg,
                                                         cells, vf4g, msk);
        k_search<<<B_GR * V_PTS / 256, 256, 0, stream>>>(vf4g, sf4g, sidxg, cells, msk);
        k_pool_m<<<B_GR * SEGS,        256, 0, stream>>>(msk, feats, partial);
        k_mlp   <<<B_GR,               128, 0, stream>>>(partial, W1, b1, W2, b2, out);
    } else {
        // ---- fallback: brute-force atomicMin path ----
        unsigned long long* mi64 = (unsigned long long*)d_ws;              // 1 MB
        float* partial = (float*)((char*)d_ws + (size_t)B_GR * V_PTS * 8); // 128 KB

        hipMemsetAsync(mi64, 0xFF, (size_t)B_GR * V_PTS * 8, stream);
        k_argmin_at<<<B_GR * FVBLKS * NSPLIT, 256, 0, stream>>>(verts, coords, mi64);
        k_pool_at  <<<B_GR * SEGS,            256, 0, stream>>>(mi64, feats, partial);
        k_mlp      <<<B_GR,                   128, 0, stream>>>(partial, W1, b1, W2, b2, out);
    }
}

// Round 11
// 281.379 us; speedup vs baseline: 1.2525x; 1.0727x over previous
//
#include <hip/hip_runtime.h>
#include <hip/hip_bf16.h>

// Problem constants (fixed by the reference): B=16, V=8192, N=2048, H=128, C_OUT=7
#define B_GR   16
#define V_PTS  8192
#define N_RES  2048
#define H_DIM  128
#define C_OUT  7
#define SEGS   16            // pool kernel: residue segments per graph
#define NB     512           // x-buckets
#define CPAD   520           // padded per-graph cellstart stride
#define BW     0.203125f     // bucket width = 104/512 = 13/64 (exact fp)
#define G_VERT 512           // sorted vertices per group
#define S_CHK  8             // slab chunks per group
#define WFIX   2.5f          // fixed slab half-width
#define RES_D  6.2f          // resolved iff computed d <= 6.2 (< 6.25 - 5e-3 fp bound)

// Ledger: r1 pk-f32 not 2x; r2 issue-bound; r3 atomicMin free; r4/r5 micro nil
// (brute 59 µs = VALU ceiling, best total 144.6). r6-r10 pruning arc: eval
// count cut works but 1-thread-per-vertex shape loses it all — 20-28
// instr/eval + 2 waves/SIMD => 55M wave-instr > brute's 42M. r11: pruned
// candidates in BRUTE's shape: fixed W=2.5 slab per 512-vertex group, split
// 8 ways -> 8192 waves (32/CU max occupancy), VPT=2 amortization, no LDS,
// packed-u64 atomicMin merge, provable resolved-check + exact fallback.

__device__ __forceinline__ int bucketof(float x) {
    int bk = (int)floorf((x + 52.0f) * (512.0f / 104.0f));
    return bk < 0 ? 0 : (bk > NB - 1 ? NB - 1 : bk);
}
__device__ __forceinline__ float lo_edge(int k) {      // k*(13/64)-52, exact fp
    return (float)k * BW - 52.0f;
}

// one candidate: bit-exact reference sequence + lexicographic (d, orig idx)
__device__ __forceinline__ void eval_one(const float4 c, int id,
                                         float vx, float vy, float vz, float vsq,
                                         float& best, int& bidx) {
    float dot = __fadd_rn(__fadd_rn(__fmul_rn(vx, c.x), __fmul_rn(vy, c.y)),
                          __fmul_rn(vz, c.z));
    float d = __fadd_rn(fmaf(-2.0f, dot, vsq), c.w);
    bool take = (d < best) || ((d == best) && (id < bidx));
    best = take ? d : best;
    bidx = take ? id : bidx;
}

// monotone-flipped (d, idx) packing — u64 < == lexicographic (d, idx) <
__device__ __forceinline__ unsigned long long packmin(float d, int idx) {
    unsigned int bits = __float_as_uint(d);
    unsigned int key  = bits ^ (unsigned int)(((int)bits >> 31) | 0x80000000);
    return ((unsigned long long)key << 32) | (unsigned int)idx;
}

// ---------------------------------------------------------------------------
// Kernel 0 (prep): per graph — counting-sort residues AND vertices by
// x-bucket (float4 x,y,z,sq; residues also keep orig idx); exclusive bucket
// starts; zero hit mask; zero fallback counter. 16 blocks x 256 threads.
// ---------------------------------------------------------------------------
__global__ __launch_bounds__(256) void k_prep(const float* __restrict__ coords,
                                              const float* __restrict__ verts,
                                              float4* __restrict__ sf4g,
                                              unsigned int* __restrict__ sidxg,
                                              unsigned int* __restrict__ cellsg,
                                              float4* __restrict__ vf4g,
                                              float* __restrict__ msk,
                                              unsigned int* __restrict__ cnt) {
    __shared__ unsigned int hist[NB];
    __shared__ unsigned int sA[NB], sB[NB];
    __shared__ unsigned int cursor[NB];
    const int b = blockIdx.x;
    const int tid = threadIdx.x;
    if (b == 0 && tid == 0) cnt[0] = 0u;

    // ---- residues ----
    for (int i = tid; i < NB; i += 256) hist[i] = 0;
    for (int i = tid; i < N_RES; i += 256) msk[b * N_RES + i] = 0.0f;
    __syncthreads();

    const float* cb = coords + (size_t)b * N_RES * 3;
    for (int i = tid; i < N_RES; i += 256)
        atomicAdd(&hist[bucketof(cb[i * 3])], 1u);
    __syncthreads();

    for (int i = tid; i < NB; i += 256) sA[i] = hist[i];
    __syncthreads();
    unsigned int* src = sA;
    unsigned int* dst = sB;
    for (int off = 1; off < NB; off <<= 1) {            // Hillis-Steele inclusive
        for (int i = tid; i < NB; i += 256)
            dst[i] = src[i] + (i >= off ? src[i - off] : 0u);
        __syncthreads();
        unsigned int* t = src; src = dst; dst = t;
    }
    for (int i = tid; i < NB; i += 256) {
        unsigned int ex = src[i] - hist[i];             // exclusive start
        cellsg[b * CPAD + i] = ex;
        cursor[i] = ex;
    }
    if (tid == 0) cellsg[b * CPAD + NB] = N_RES;
    __syncthreads();

    for (int i = tid; i < N_RES; i += 256) {
        float x = cb[i * 3 + 0];
        float y = cb[i * 3 + 1];
        float z = cb[i * 3 + 2];
        float csq = __fadd_rn(__fadd_rn(__fmul_rn(x, x), __fmul_rn(y, y)), __fmul_rn(z, z));
        unsigned int pos = atomicAdd(&cursor[bucketof(x)], 1u);
        sf4g[(size_t)b * N_RES + pos] = make_float4(x, y, z, csq);
        sidxg[(size_t)b * N_RES + pos] = (unsigned int)i;
    }
    __syncthreads();

    // ---- vertices (reuse hist/scan/cursor) ----
    for (int i = tid; i < NB; i += 256) hist[i] = 0;
    __syncthreads();
    const float* vb = verts + (size_t)b * V_PTS * 3;
    for (int i = tid; i < V_PTS; i += 256)
        atomicAdd(&hist[bucketof(vb[i * 3])], 1u);
    __syncthreads();
    for (int i = tid; i < NB; i += 256) sA[i] = hist[i];
    __syncthreads();
    src = sA; dst = sB;
    for (int off = 1; off < NB; off <<= 1) {
        for (int i = tid; i < NB; i += 256)
            dst[i] = src[i] + (i >= off ? src[i - off] : 0u);
        __syncthreads();
        unsigned int* t = src; src = dst; dst = t;
    }
    for (int i = tid; i < NB; i += 256)
        cursor[i] = src[i] - hist[i];
    __syncthreads();
    for (int i = tid; i < V_PTS; i += 256) {
        float x = vb[i * 3 + 0];
        float y = vb[i * 3 + 1];
        float z = vb[i * 3 + 2];
        float vsq = __fadd_rn(__fadd_rn(__fmul_rn(x, x), __fmul_rn(y, y)), __fmul_rn(z, z));
        unsigned int pos = atomicAdd(&cursor[bucketof(x)], 1u);
        vf4g[(size_t)b * V_PTS + pos] = make_float4(x, y, z, vsq);
    }
}

// ---------------------------------------------------------------------------
// Kernel 1 (search): block (group g, chunk s). Group = 512 consecutive
// sorted vertices; slab = [lo_edge(kfirst)-W, lo_edge(klast+1)+W] mapped to
// a contiguous sorted-residue range [j0,j1), chunk s scans its 1/8. Thread
// handles 2 vertices (t, t+256); per j: one broadcast float4 + u32 from
// L1/L2 (no LDS), 2 bit-exact evals with lexicographic (d, orig idx).
// Per-vertex partials merged across the 8 chunks via atomicMin on packed
// (flipped-d | orig-idx) u64 — exact np.argmin semantics (r0-r4 proven).
// Grid 2048 blocks x 256 threads = 8192 waves = 32 waves/CU (max).
// ---------------------------------------------------------------------------
__global__ __launch_bounds__(256, 8) void k_search(const float4* __restrict__ vf4g,
                                                   const float4* __restrict__ sf4g,
                                                   const unsigned int* __restrict__ sidxg,
                                                   const unsigned int* __restrict__ cellsg,
                                                   unsigned long long* __restrict__ mi64) {
    const int blk = blockIdx.x;
    const int s   = blk & (S_CHK - 1);
    const int grp = blk >> 3;                           // global group 0..B*16-1
    const int b   = grp >> 4;                           // 16 groups per graph
    const int g0  = grp << 9;                           // global sorted-vertex base

    // slab from group bucket extent (bucket edges are exact fp; clamping at
    // array ends makes j0=0 / j1=N, which only widens the scan)
    const int kf = bucketof(vf4g[g0].x);
    const int kl = bucketof(vf4g[g0 + G_VERT - 1].x);
    const int j0 = (int)cellsg[b * CPAD + bucketof(lo_edge(kf) - WFIX)];
    const int j1 = (int)cellsg[b * CPAD + bucketof(lo_edge(kl + 1) + WFIX) + 1];
    const int len = j1 - j0;
    const int jA = j0 + (len * s) / S_CHK;
    const int jB = j0 + (len * (s + 1)) / S_CHK;

    const int t = threadIdx.x;
    const float4 v0 = vf4g[g0 + t];
    const float4 v1 = vf4g[g0 + t + 256];

    float b0 = 3.402823466e+38f, b1 = 3.402823466e+38f;
    int   i0 = 0, i1 = 0;
    const float4* sp = sf4g + (size_t)b * N_RES;
    const unsigned int* ip = sidxg + (size_t)b * N_RES;

#pragma unroll 2
    for (int j = jA; j < jB; ++j) {
        const float4 c = sp[j];                         // broadcast (all lanes same)
        const int id = (int)ip[j];
        eval_one(c, id, v0.x, v0.y, v0.z, v0.w, b0, i0);
        eval_one(c, id, v1.x, v1.y, v1.z, v1.w, b1, i1);
    }

    atomicMin(&mi64[g0 + t],       packmin(b0, i0));
    atomicMin(&mi64[g0 + t + 256], packmin(b1, i1));
}

// ---------------------------------------------------------------------------
// Kernel 1b (finalize): per sorted vertex, read the merged winner. If its
// computed d <= 6.2 it is provably the GLOBAL argmin (every unscanned
// residue has true dist^2 > 6.25 by slab geometry, computed d' >= 6.25-5e-3
// > 6.2) -> scatter into hit mask. Else append to the fallback list.
// Key compare done in flipped space (monotone). 512 blocks x 256 threads.
// ---------------------------------------------------------------------------
__global__ __launch_bounds__(256) void k_finalize(const unsigned long long* __restrict__ mi64,
                                                  float* __restrict__ msk,
                                                  unsigned int* __restrict__ list,
                                                  unsigned int* __restrict__ cnt) {
    const int p = blockIdx.x * 256 + threadIdx.x;       // 0..B*V-1
    const int b = p >> 13;
    const unsigned long long w = mi64[p];
    const unsigned int key  = (unsigned int)(w >> 32);
    const unsigned int kthr = __float_as_uint(RES_D) ^ 0x80000000u;  // flip(6.2)
    if (key <= kthr) {
        msk[b * N_RES + (unsigned int)(w & 0xFFFFFFFFu)] = 1.0f;
    } else {
        unsigned int slot = atomicAdd(cnt, 1u);
        list[slot] = (unsigned int)p;
    }
}

// ---------------------------------------------------------------------------
// Kernel 1c (fallback): one wave per unresolved vertex (grid-stride over the
// dynamic count — graph-legal). Full 2048-residue scan: lane l takes
// j = l, l+64, ... (coalesced), lexicographic in-lane, packed-u64 shuffle
// reduce across the wave -> exact np.argmin. 2048 blocks x 64 threads.
// ---------------------------------------------------------------------------
__global__ __launch_bounds__(64) void k_fallback(const float4* __restrict__ vf4g,
                                                 const float4* __restrict__ sf4g,
                                                 const unsigned int* __restrict__ sidxg,
                                                 const unsigned int* __restrict__ list,
                                                 const unsigned int* __restrict__ cnt,
                                                 float* __restrict__ msk) {
    const unsigned int n = *cnt;
    const int lane = threadIdx.x;
    for (unsigned int i = blockIdx.x; i < n; i += gridDim.x) {
        const unsigned int p = list[i];
        const int b = (int)(p >> 13);
        const float4 v = vf4g[p];
        float best = 3.402823466e+38f;
        int bidx = 0;
        const float4* sp = sf4g + (size_t)b * N_RES;
        const unsigned int* ip = sidxg + (size_t)b * N_RES;
        for (int j = lane; j < N_RES; j += 64)
            eval_one(sp[j], (int)ip[j], v.x, v.y, v.z, v.w, best, bidx);
        unsigned long long pk = packmin(best, bidx);
#pragma unroll
        for (int o = 1; o < 64; o <<= 1) {
            unsigned long long q = __shfl_xor(pk, o);
            pk = q < pk ? q : pk;
        }
        if (lane == 0)
            msk[b * N_RES + (unsigned int)(pk & 0xFFFFFFFFu)] = 1.0f;
    }
}

// ---------------------------------------------------------------------------
// Kernel 2: masked-sum a 128-residue slice of feats with float4 loads.
// ---------------------------------------------------------------------------
__global__ __launch_bounds__(256) void k_pool_m(const float* __restrict__ msk,
                                                const float* __restrict__ feats,
                                                float* __restrict__ partial) {
    __shared__ float sm[N_RES / SEGS];
    __shared__ float4 red[8][32];
    const int b   = blockIdx.x >> 4;
    const int seg = blockIdx.x & (SEGS - 1);
    const int n0  = seg * (N_RES / SEGS);

    if (threadIdx.x < N_RES / SEGS) sm[threadIdx.x] = msk[b * N_RES + n0 + threadIdx.x];
    __syncthreads();

    const int q = threadIdx.x & 31;
    const int s = threadIdx.x >> 5;
    const float4* fb4 = (const float4*)(feats + ((size_t)b * N_RES + n0) * H_DIM);

    float4 acc = make_float4(0.f, 0.f, 0.f, 0.f);
#pragma unroll
    for (int n = 0; n < N_RES / SEGS / 8; ++n) {
        const int nn = s + n * 8;
        const float m = sm[nn];
        const float4 f = fb4[(size_t)nn * 32 + q];
        acc.x = fmaf(f.x, m, acc.x);
        acc.y = fmaf(f.y, m, acc.y);
        acc.z = fmaf(f.z, m, acc.z);
        acc.w = fmaf(f.w, m, acc.w);
    }
    red[s][q] = acc;
    __syncthreads();

    if (s == 0) {
        float4 t = acc;
#pragma unroll
        for (int i = 1; i < 8; ++i) {
            t.x += red[i][q].x; t.y += red[i][q].y;
            t.z += red[i][q].z; t.w += red[i][q].w;
        }
        ((float4*)partial)[((size_t)b * SEGS + seg) * 32 + q] = t;
    }
}

// ---------------------------------------------------------------------------
// Fallback path (small workspace): brute-force atomicMin kernels (r0).
// ---------------------------------------------------------------------------
#define NSPLIT 16
#define NL     (N_RES / NSPLIT)
#define FVPT   8
#define FVBLK  (256 * FVPT)
#define FVBLKS (V_PTS / FVBLK)
__global__ __launch_bounds__(256, 4) void k_argmin_at(const float* __restrict__ verts,
                                                      const float* __restrict__ coords,
                                                      unsigned long long* __restrict__ mi64) {
    __shared__ float4 sc[NL];
    const int b  = blockIdx.x / (FVBLKS * NSPLIT);
    const int r  = blockIdx.x % (FVBLKS * NSPLIT);
    const int vb = r / NSPLIT;
    const int ns = r % NSPLIT;

    const float* cbase = coords + ((size_t)b * N_RES + ns * NL) * 3;
    if (threadIdx.x < NL) {
        const int i = threadIdx.x;
        float x = cbase[i * 3 + 0];
        float y = cbase[i * 3 + 1];
        float z = cbase[i * 3 + 2];
        float csq = __fadd_rn(__fadd_rn(__fmul_rn(x, x), __fmul_rn(y, y)), __fmul_rn(z, z));
        sc[i] = make_float4(x, y, z, csq);
    }
    __syncthreads();

    const int vbase = vb * FVBLK + threadIdx.x;
    const float* vp = verts + (size_t)b * V_PTS * 3;

    float vx[FVPT], vy[FVPT], vz[FVPT], vsq[FVPT], best[FVPT];
    int bi[FVPT];
#pragma unroll
    for (int k = 0; k < FVPT; ++k) {
        const int v = vbase + k * 256;
        vx[k] = vp[v * 3 + 0];
        vy[k] = vp[v * 3 + 1];
        vz[k] = vp[v * 3 + 2];
        vsq[k] = __fadd_rn(__fadd_rn(__fmul_rn(vx[k], vx[k]), __fmul_rn(vy[k], vy[k])),
                           __fmul_rn(vz[k], vz[k]));
        best[k] = 3.402823466e+38f;
        bi[k] = 0;
    }
#pragma unroll 2
    for (int n = 0; n < NL; ++n) {
        const float4 c = sc[n];
#pragma unroll
        for (int k = 0; k < FVPT; ++k) {
            float dot = __fadd_rn(__fadd_rn(__fmul_rn(vx[k], c.x), __fmul_rn(vy[k], c.y)),
                                  __fmul_rn(vz[k], c.z));
            float d = __fadd_rn(fmaf(-2.0f, dot, vsq[k]), c.w);
            bool m = d < best[k];
            best[k] = m ? d : best[k];
            bi[k]   = m ? n : bi[k];
        }
    }
#pragma unroll
    for (int k = 0; k < FVPT; ++k) {
        unsigned int bits = __float_as_uint(best[k]);
        unsigned int key  = bits ^ (unsigned int)(((int)bits >> 31) | 0x80000000);
        unsigned long long packed =
            ((unsigned long long)key << 32) | (unsigned int)(ns * NL + bi[k]);
        atomicMin(&mi64[(size_t)b * V_PTS + vbase + k * 256], packed);
    }
}

__global__ __launch_bounds__(256) void k_pool_at(const unsigned long long* __restrict__ mi64,
                                                 const float* __restrict__ feats,
                                                 float* __restrict__ partial) {
    __shared__ float msk[N_RES];
    __shared__ float4 red[8][32];
    const int b   = blockIdx.x >> 4;
    const int seg = blockIdx.x & (SEGS - 1);

    for (int i = threadIdx.x; i < N_RES; i += 256) msk[i] = 0.0f;
    __syncthreads();
    const unsigned long long* mb = mi64 + (size_t)b * V_PTS;
    for (int v = threadIdx.x; v < V_PTS; v += 256)
        msk[(unsigned int)mb[v]] = 1.0f;
    __syncthreads();

    const int q = threadIdx.x & 31;
    const int s = threadIdx.x >> 5;
    const int n0 = seg * (N_RES / SEGS);
    const float4* fb4 = (const float4*)(feats + ((size_t)b * N_RES + n0) * H_DIM);

    float4 acc = make_float4(0.f, 0.f, 0.f, 0.f);
#pragma unroll
    for (int n = 0; n < N_RES / SEGS / 8; ++n) {
        const int nn = s + n * 8;
        const float m = msk[n0 + nn];
        const float4 f = fb4[(size_t)nn * 32 + q];
        acc.x = fmaf(f.x, m, acc.x);
        acc.y = fmaf(f.y, m, acc.y);
        acc.z = fmaf(f.z, m, acc.z);
        acc.w = fmaf(f.w, m, acc.w);
    }
    red[s][q] = acc;
    __syncthreads();
    if (s == 0) {
        float4 t = acc;
#pragma unroll
        for (int i = 1; i < 8; ++i) {
            t.x += red[i][q].x; t.y += red[i][q].y;
            t.z += red[i][q].z; t.w += red[i][q].w;
        }
        ((float4*)partial)[((size_t)b * SEGS + seg) * 32 + q] = t;
    }
}

// ---------------------------------------------------------------------------
// Kernel 3: per-graph pooled reduce + MLP. 16 blocks x 128 threads.
// ---------------------------------------------------------------------------
__global__ __launch_bounds__(128) void k_mlp(const float* __restrict__ partial,
                                             const float* __restrict__ W1,
                                             const float* __restrict__ b1,
                                             const float* __restrict__ W2,
                                             const float* __restrict__ b2,
                                             float* __restrict__ out) {
    __shared__ float pooled[H_DIM];
    __shared__ float h1[H_DIM];
    const int b = blockIdx.x;
    const int j = threadIdx.x;

    float s = 0.0f;
#pragma unroll
    for (int g = 0; g < SEGS; ++g)
        s += partial[((size_t)b * SEGS + g) * H_DIM + j];
    pooled[j] = s;
    __syncthreads();

    float acc = b1[j];
#pragma unroll 8
    for (int hh = 0; hh < H_DIM; ++hh)
        acc = fmaf(pooled[hh], W1[hh * H_DIM + j], acc);
    h1[j] = fmaxf(acc, 0.0f);
    __syncthreads();

    if (j < C_OUT) {
        float o = b2[j];
#pragma unroll 8
        for (int hh = 0; hh < H_DIM; ++hh)
            o = fmaf(h1[hh], W2[hh * C_OUT + j], o);
        out[(size_t)b * C_OUT + j] = o;
    }
}

extern "C" void kernel_launch(void* const* d_in, const int* in_sizes, int n_in,
                              void* d_out, int out_size, void* d_ws, size_t ws_size,
                              hipStream_t stream) {
    const float* verts  = (const float*)d_in[0];   // [B,V,3]
    const float* coords = (const float*)d_in[1];   // [B,N,3]
    const float* feats  = (const float*)d_in[2];   // [B,N,H]
    const float* W1     = (const float*)d_in[3];   // [H,H]
    const float* b1     = (const float*)d_in[4];   // [H]
    const float* W2     = (const float*)d_in[5];   // [H,C_OUT]
    const float* b2     = (const float*)d_in[6];   // [C_OUT]
    float* out = (float*)d_out;                    // [B,C_OUT]

    // workspace layout (~4.9 MB)
    const size_t vf4_bytes  = (size_t)B_GR * V_PTS * 16;       // 2 MB
    const size_t sf4_bytes  = (size_t)B_GR * N_RES * 16;       // 512 KB
    const size_t sidx_bytes = (size_t)B_GR * N_RES * 4;        // 128 KB
    const size_t cell_bytes = (size_t)B_GR * CPAD * 4;         // ~33 KB
    const size_t msk_bytes  = (size_t)B_GR * N_RES * 4;        // 128 KB
    const size_t pp_bytes   = (size_t)B_GR * SEGS * H_DIM * 4; // 128 KB
    const size_t mi_bytes   = (size_t)B_GR * V_PTS * 8;        // 1 MB
    const size_t list_bytes = (size_t)B_GR * V_PTS * 4;        // 512 KB
    const size_t cnt_bytes  = 256;
    const size_t need = vf4_bytes + sf4_bytes + sidx_bytes + cell_bytes +
                        msk_bytes + pp_bytes + mi_bytes + list_bytes + cnt_bytes;

    if (ws_size >= need) {
        char* p = (char*)d_ws;
        float4*             vf4g  = (float4*)p;             p += vf4_bytes;
        float4*             sf4g  = (float4*)p;             p += sf4_bytes;
        unsigned int*       sidxg = (unsigned int*)p;       p += sidx_bytes;
        unsigned int*       cells = (unsigned int*)p;       p += cell_bytes;
        float*              msk   = (float*)p;              p += msk_bytes;
        float*              partial = (float*)p;            p += pp_bytes;
        unsigned long long* mi64  = (unsigned long long*)p; p += mi_bytes;
        unsigned int*       list  = (unsigned int*)p;       p += list_bytes;
        unsigned int*       cnt   = (unsigned int*)p;

        hipMemsetAsync(mi64, 0xFF, mi_bytes, stream);
        k_prep    <<<B_GR,                 256, 0, stream>>>(coords, verts, sf4g, sidxg,
                                                             cells, vf4g, msk, cnt);
        k_search  <<<B_GR * 16 * S_CHK,    256, 0, stream>>>(vf4g, sf4g, sidxg, cells, mi64);
        k_finalize<<<B_GR * V_PTS / 256,   256, 0, stream>>>(mi64, msk, list, cnt);
        k_fallback<<<2048,                  64, 0, stream>>>(vf4g, sf4g, sidxg, list, cnt, msk);
        k_pool_m  <<<B_GR * SEGS,          256, 0, stream>>>(msk, feats, partial);
        k_mlp     <<<B_GR,                 128, 0, stream>>>(partial, W1, b1, W2, b2, out);
    } else {
        // ---- fallback: brute-force atomicMin path ----
        unsigned long long* mi64 = (unsigned long long*)d_ws;              // 1 MB
        float* partial = (float*)((char*)d_ws + (size_t)B_GR * V_PTS * 8); // 128 KB

        hipMemsetAsync(mi64, 0xFF, (size_t)B_GR * V_PTS * 8, stream);
        k_argmin_at<<<B_GR * FVBLKS * NSPLIT, 256, 0, stream>>>(verts, coords, mi64);
        k_pool_at  <<<B_GR * SEGS,            256, 0, stream>>>(mi64, feats, partial);
        k_mlp      <<<B_GR,                   128, 0, stream>>>(partial, W1, b1, W2, b2, out);
    }
}

// Round 12
// 198.231 us; speedup vs baseline: 1.7779x; 1.4194x over previous
//
#include <hip/hip_runtime.h>
#include <hip/hip_bf16.h>

// Problem constants (fixed by the reference): B=16, V=8192, N=2048, H=128, C_OUT=7
#define B_GR   16
#define V_PTS  8192
#define N_RES  2048
#define H_DIM  128
#define C_OUT  7
#define SEGS   16
#define NB     512           // x-buckets
#define CPAD   520           // padded per-graph cellstart stride
#define BW     0.203125f     // bucket width = 104/512 = 13/64 (exact fp)
#define G_VERT 512           // sorted vertices per search group
#define S_CHK  8             // slab chunks per group
#define WFIX   2.5f          // fixed slab half-width (pass 1)
#define RES_D  6.2f          // resolved iff computed d <= 6.2 (< 6.25 - 5e-3 fp bound)

// Ledger: r1 pk-f32 not 2x; r2 issue-bound; r3 atomics free; r4/r5 micro nil
// (brute 59 µs, best total 144.6). r6-r10: eval-count pruning works but
// 1-thread-per-vertex shape loses it (20-28 instr/eval, 2 waves/SIMD).
// r11: search in brute shape OK, but k_fallback = 111 µs (25-35K unresolved,
// full-scan, 2 waves/SIMD ILP=1) and prep (16 blocks) suspected ~40-60 µs
// hidden. r12: slab-bounded wide fallback (W2 from pass-1 best — validated
// bound) + prep split into 3 wide kernels. Search/finalize/pool/mlp frozen.

__device__ __forceinline__ int bucketof(float x) {
    int bk = (int)floorf((x + 52.0f) * (512.0f / 104.0f));
    return bk < 0 ? 0 : (bk > NB - 1 ? NB - 1 : bk);
}
__device__ __forceinline__ float lo_edge(int k) {      // k*(13/64)-52, exact fp
    return (float)k * BW - 52.0f;
}

// one candidate: bit-exact reference sequence + lexicographic (d, orig idx)
__device__ __forceinline__ void eval_one(const float4 c, int id,
                                         float vx, float vy, float vz, float vsq,
                                         float& best, int& bidx) {
    float dot = __fadd_rn(__fadd_rn(__fmul_rn(vx, c.x), __fmul_rn(vy, c.y)),
                          __fmul_rn(vz, c.z));
    float d = __fadd_rn(fmaf(-2.0f, dot, vsq), c.w);
    bool take = (d < best) || ((d == best) && (id < bidx));
    best = take ? d : best;
    bidx = take ? id : bidx;
}

// monotone-flipped (d, idx) packing — u64 < == lexicographic (d, idx) <
__device__ __forceinline__ unsigned long long packmin(float d, int idx) {
    unsigned int bits = __float_as_uint(d);
    unsigned int key  = bits ^ (unsigned int)(((int)bits >> 31) | 0x80000000);
    return ((unsigned long long)key << 32) | (unsigned int)idx;
}

// ---------------------------------------------------------------------------
// Kernel 0a (hist): 256 blocks (16/graph). Global-atomic histograms of
// residues (128/block) and vertices (512/block) by x-bucket; zero msk slice
// and the fallback counter. hist arrays are memset-zeroed by a graph node.
// ---------------------------------------------------------------------------
__global__ __launch_bounds__(256) void k_hist(const float* __restrict__ coords,
                                              const float* __restrict__ verts,
                                              unsigned int* __restrict__ histR,
                                              unsigned int* __restrict__ histV,
                                              float* __restrict__ msk,
                                              unsigned int* __restrict__ cnt) {
    const int b    = blockIdx.x >> 4;
    const int part = blockIdx.x & 15;
    const int tid  = threadIdx.x;
    if (blockIdx.x == 0 && tid == 0) cnt[0] = 0u;
    if (tid < 128) msk[b * N_RES + part * 128 + tid] = 0.0f;

    const float* cb = coords + (size_t)b * N_RES * 3;
    if (tid < 128)
        atomicAdd(&histR[b * NB + bucketof(cb[(part * 128 + tid) * 3])], 1u);
    const float* vb = verts + (size_t)b * V_PTS * 3;
    for (int i = tid; i < 512; i += 256)
        atomicAdd(&histV[b * NB + bucketof(vb[(part * 512 + i) * 3])], 1u);
}

// ---------------------------------------------------------------------------
// Kernel 0b (scan): 16 blocks (1/graph). LDS Hillis-Steele scan of both
// histograms -> residue cellstarts + scatter cursors.
// ---------------------------------------------------------------------------
__global__ __launch_bounds__(256) void k_scan(const unsigned int* __restrict__ histR,
                                              const unsigned int* __restrict__ histV,
                                              unsigned int* __restrict__ cellsg,
                                              unsigned int* __restrict__ cursR,
                                              unsigned int* __restrict__ cursV) {
    __shared__ unsigned int sA[NB], sB[NB];
    const int b = blockIdx.x;
    const int tid = threadIdx.x;

    for (int i = tid; i < NB; i += 256) sA[i] = histR[b * NB + i];
    __syncthreads();
    unsigned int* src = sA;
    unsigned int* dst = sB;
    for (int off = 1; off < NB; off <<= 1) {
        for (int i = tid; i < NB; i += 256)
            dst[i] = src[i] + (i >= off ? src[i - off] : 0u);
        __syncthreads();
        unsigned int* t = src; src = dst; dst = t;
    }
    for (int i = tid; i < NB; i += 256) {
        unsigned int ex = src[i] - histR[b * NB + i];   // exclusive start
        cellsg[b * CPAD + i] = ex;
        cursR[b * NB + i] = ex;
    }
    if (tid == 0) cellsg[b * CPAD + NB] = N_RES;
    __syncthreads();

    for (int i = tid; i < NB; i += 256) sA[i] = histV[b * NB + i];
    __syncthreads();
    src = sA; dst = sB;
    for (int off = 1; off < NB; off <<= 1) {
        for (int i = tid; i < NB; i += 256)
            dst[i] = src[i] + (i >= off ? src[i - off] : 0u);
        __syncthreads();
        unsigned int* t = src; src = dst; dst = t;
    }
    for (int i = tid; i < NB; i += 256)
        cursV[b * NB + i] = src[i] - histV[b * NB + i];
}

// ---------------------------------------------------------------------------
// Kernel 0c (scatter): 256 blocks (16/graph). Counting-sort placement via
// global-cursor atomicAdd; squared norms use the exact reference sequence.
// Within-bucket order arbitrary — selection is lexicographic.
// ---------------------------------------------------------------------------
__global__ __launch_bounds__(256) void k_scatter(const float* __restrict__ coords,
                                                 const float* __restrict__ verts,
                                                 float4* __restrict__ sf4g,
                                                 unsigned int* __restrict__ sidxg,
                                                 float4* __restrict__ vf4g,
                                                 unsigned int* __restrict__ cursR,
                                                 unsigned int* __restrict__ cursV) {
    const int b    = blockIdx.x >> 4;
    const int part = blockIdx.x & 15;
    const int tid  = threadIdx.x;

    const float* cb = coords + (size_t)b * N_RES * 3;
    if (tid < 128) {
        const int i = part * 128 + tid;
        float x = cb[i * 3 + 0], y = cb[i * 3 + 1], z = cb[i * 3 + 2];
        float csq = __fadd_rn(__fadd_rn(__fmul_rn(x, x), __fmul_rn(y, y)), __fmul_rn(z, z));
        unsigned int pos = atomicAdd(&cursR[b * NB + bucketof(x)], 1u);
        sf4g[(size_t)b * N_RES + pos] = make_float4(x, y, z, csq);
        sidxg[(size_t)b * N_RES + pos] = (unsigned int)i;
    }
    const float* vb = verts + (size_t)b * V_PTS * 3;
    for (int ii = tid; ii < 512; ii += 256) {
        const int i = part * 512 + ii;
        float x = vb[i * 3 + 0], y = vb[i * 3 + 1], z = vb[i * 3 + 2];
        float vsq = __fadd_rn(__fadd_rn(__fmul_rn(x, x), __fmul_rn(y, y)), __fmul_rn(z, z));
        unsigned int pos = atomicAdd(&cursV[b * NB + bucketof(x)], 1u);
        vf4g[(size_t)b * V_PTS + pos] = make_float4(x, y, z, vsq);
    }
}

// ---------------------------------------------------------------------------
// Kernel 1 (search): FROZEN from r11. Group of 512 sorted vertices, fixed
// W=2.5 slab split into 8 chunks, VPT=2, broadcast global reads, packed-u64
// atomicMin merge. 2048 blocks x 256 thr = 32 waves/CU.
// ---------------------------------------------------------------------------
__global__ __launch_bounds__(256, 8) void k_search(const float4* __restrict__ vf4g,
                                                   const float4* __restrict__ sf4g,
                                                   const unsigned int* __restrict__ sidxg,
                                                   const unsigned int* __restrict__ cellsg,
                                                   unsigned long long* __restrict__ mi64) {
    const int blk = blockIdx.x;
    const int s   = blk & (S_CHK - 1);
    const int grp = blk >> 3;
    const int b   = grp >> 4;
    const int g0  = grp << 9;

    const int kf = bucketof(vf4g[g0].x);
    const int kl = bucketof(vf4g[g0 + G_VERT - 1].x);
    const int j0 = (int)cellsg[b * CPAD + bucketof(lo_edge(kf) - WFIX)];
    const int j1 = (int)cellsg[b * CPAD + bucketof(lo_edge(kl + 1) + WFIX) + 1];
    const int len = j1 - j0;
    const int jA = j0 + (len * s) / S_CHK;
    const int jB = j0 + (len * (s + 1)) / S_CHK;

    const int t = threadIdx.x;
    const float4 v0 = vf4g[g0 + t];
    const float4 v1 = vf4g[g0 + t + 256];

    float b0 = 3.402823466e+38f, b1 = 3.402823466e+38f;
    int   i0 = 0, i1 = 0;
    const float4* sp = sf4g + (size_t)b * N_RES;
    const unsigned int* ip = sidxg + (size_t)b * N_RES;

#pragma unroll 2
    for (int j = jA; j < jB; ++j) {
        const float4 c = sp[j];
        const int id = (int)ip[j];
        eval_one(c, id, v0.x, v0.y, v0.z, v0.w, b0, i0);
        eval_one(c, id, v1.x, v1.y, v1.z, v1.w, b1, i1);
    }

    atomicMin(&mi64[g0 + t],       packmin(b0, i0));
    atomicMin(&mi64[g0 + t + 256], packmin(b1, i1));
}

// ---------------------------------------------------------------------------
// Kernel 1b (finalize): FROZEN from r11. d <= 6.2 provably global -> mask;
// else append to fallback list.
// ---------------------------------------------------------------------------
__global__ __launch_bounds__(256) void k_finalize(const unsigned long long* __restrict__ mi64,
                                                  float* __restrict__ msk,
                                                  unsigned int* __restrict__ list,
                                                  unsigned int* __restrict__ cnt) {
    const int p = blockIdx.x * 256 + threadIdx.x;
    const int b = p >> 13;
    const unsigned long long w = mi64[p];
    const unsigned int key  = (unsigned int)(w >> 32);
    const unsigned int kthr = __float_as_uint(RES_D) ^ 0x80000000u;
    if (key <= kthr) {
        msk[b * N_RES + (unsigned int)(w & 0xFFFFFFFFu)] = 1.0f;
    } else {
        unsigned int slot = atomicAdd(cnt, 1u);
        list[slot] = (unsigned int)p;
    }
}

// ---------------------------------------------------------------------------
// Kernel 1c (fallback, NEW): one WAVE per unresolved vertex, 8192 waves
// grid-striding. Slab-bounded: pass-1 winner distance d1 gives
// W2 = sqrt(min(d1,4e4)+1)+1/16 — the r7-validated bound: any residue that
// could beat or tie the winner has |dx| < W2 (true d^2 <= d1+4e-3 < d1+1),
// and the winner itself lies inside, so the range is non-empty. d1 >= 4e4
// (incl. empty-slab FLT_MAX) clamps W2 ~ 200 -> full scan. Lanes stride the
// per-wave-uniform range coalesced; packed-u64 shuffle reduce -> exact
// np.argmin. 2048 blocks x 256 threads (4 waves/block).
// ---------------------------------------------------------------------------
__global__ __launch_bounds__(256) void k_fallback(const float4* __restrict__ vf4g,
                                                  const float4* __restrict__ sf4g,
                                                  const unsigned int* __restrict__ sidxg,
                                                  const unsigned int* __restrict__ cellsg,
                                                  const unsigned long long* __restrict__ mi64,
                                                  const unsigned int* __restrict__ list,
                                                  const unsigned int* __restrict__ cnt,
                                                  float* __restrict__ msk) {
    const unsigned int n = *cnt;
    const int lane = threadIdx.x & 63;
    const unsigned int gw = (blockIdx.x << 2) | (unsigned int)(threadIdx.x >> 6);
    const unsigned int stride = gridDim.x << 2;

    for (unsigned int i = gw; i < n; i += stride) {
        const unsigned int p = list[i];
        const int b = (int)(p >> 13);
        const float4 v = vf4g[p];
        const unsigned int key = (unsigned int)(mi64[p] >> 32);
        const float d1 = __uint_as_float(key >= 0x80000000u ? (key ^ 0x80000000u) : ~key);
        const float W2 = sqrtf(fminf(d1, 40000.0f) + 1.0f) + 0.0625f;
        const int j0 = (int)cellsg[b * CPAD + bucketof(v.x - W2)];
        const int j1 = (int)cellsg[b * CPAD + bucketof(v.x + W2) + 1];

        float best = 3.402823466e+38f;
        int bidx = 0;
        const float4* sp = sf4g + (size_t)b * N_RES;
        const unsigned int* ip = sidxg + (size_t)b * N_RES;
        for (int j = j0 + lane; j < j1; j += 64)
            eval_one(sp[j], (int)ip[j], v.x, v.y, v.z, v.w, best, bidx);

        unsigned long long pk = packmin(best, bidx);
#pragma unroll
        for (int o = 1; o < 64; o <<= 1) {
            unsigned long long q = __shfl_xor(pk, o);
            pk = q < pk ? q : pk;
        }
        if (lane == 0)
            msk[b * N_RES + (unsigned int)(pk & 0xFFFFFFFFu)] = 1.0f;
    }
}

// ---------------------------------------------------------------------------
// Kernel 2: masked-sum a 128-residue slice of feats with float4 loads.
// ---------------------------------------------------------------------------
__global__ __launch_bounds__(256) void k_pool_m(const float* __restrict__ msk,
                                                const float* __restrict__ feats,
                                                float* __restrict__ partial) {
    __shared__ float sm[N_RES / SEGS];
    __shared__ float4 red[8][32];
    const int b   = blockIdx.x >> 4;
    const int seg = blockIdx.x & (SEGS - 1);
    const int n0  = seg * (N_RES / SEGS);

    if (threadIdx.x < N_RES / SEGS) sm[threadIdx.x] = msk[b * N_RES + n0 + threadIdx.x];
    __syncthreads();

    const int q = threadIdx.x & 31;
    const int s = threadIdx.x >> 5;
    const float4* fb4 = (const float4*)(feats + ((size_t)b * N_RES + n0) * H_DIM);

    float4 acc = make_float4(0.f, 0.f, 0.f, 0.f);
#pragma unroll
    for (int n = 0; n < N_RES / SEGS / 8; ++n) {
        const int nn = s + n * 8;
        const float m = sm[nn];
        const float4 f = fb4[(size_t)nn * 32 + q];
        acc.x = fmaf(f.x, m, acc.x);
        acc.y = fmaf(f.y, m, acc.y);
        acc.z = fmaf(f.z, m, acc.z);
        acc.w = fmaf(f.w, m, acc.w);
    }
    red[s][q] = acc;
    __syncthreads();

    if (s == 0) {
        float4 t = acc;
#pragma unroll
        for (int i = 1; i < 8; ++i) {
            t.x += red[i][q].x; t.y += red[i][q].y;
            t.z += red[i][q].z; t.w += red[i][q].w;
        }
        ((float4*)partial)[((size_t)b * SEGS + seg) * 32 + q] = t;
    }
}

// ---------------------------------------------------------------------------
// Fallback path (small workspace): brute-force atomicMin kernels (r0).
// ---------------------------------------------------------------------------
#define NSPLIT 16
#define NL     (N_RES / NSPLIT)
#define FVPT   8
#define FVBLK  (256 * FVPT)
#define FVBLKS (V_PTS / FVBLK)
__global__ __launch_bounds__(256, 4) void k_argmin_at(const float* __restrict__ verts,
                                                      const float* __restrict__ coords,
                                                      unsigned long long* __restrict__ mi64) {
    __shared__ float4 sc[NL];
    const int b  = blockIdx.x / (FVBLKS * NSPLIT);
    const int r  = blockIdx.x % (FVBLKS * NSPLIT);
    const int vb = r / NSPLIT;
    const int ns = r % NSPLIT;

    const float* cbase = coords + ((size_t)b * N_RES + ns * NL) * 3;
    if (threadIdx.x < NL) {
        const int i = threadIdx.x;
        float x = cbase[i * 3 + 0];
        float y = cbase[i * 3 + 1];
        float z = cbase[i * 3 + 2];
        float csq = __fadd_rn(__fadd_rn(__fmul_rn(x, x), __fmul_rn(y, y)), __fmul_rn(z, z));
        sc[i] = make_float4(x, y, z, csq);
    }
    __syncthreads();

    const int vbase = vb * FVBLK + threadIdx.x;
    const float* vp = verts + (size_t)b * V_PTS * 3;

    float vx[FVPT], vy[FVPT], vz[FVPT], vsq[FVPT], best[FVPT];
    int bi[FVPT];
#pragma unroll
    for (int k = 0; k < FVPT; ++k) {
        const int v = vbase + k * 256;
        vx[k] = vp[v * 3 + 0];
        vy[k] = vp[v * 3 + 1];
        vz[k] = vp[v * 3 + 2];
        vsq[k] = __fadd_rn(__fadd_rn(__fmul_rn(vx[k], vx[k]), __fmul_rn(vy[k], vy[k])),
                           __fmul_rn(vz[k], vz[k]));
        best[k] = 3.402823466e+38f;
        bi[k] = 0;
    }
#pragma unroll 2
    for (int n = 0; n < NL; ++n) {
        const float4 c = sc[n];
#pragma unroll
        for (int k = 0; k < FVPT; ++k) {
            float dot = __fadd_rn(__fadd_rn(__fmul_rn(vx[k], c.x), __fmul_rn(vy[k], c.y)),
                                  __fmul_rn(vz[k], c.z));
            float d = __fadd_rn(fmaf(-2.0f, dot, vsq[k]), c.w);
            bool m = d < best[k];
            best[k] = m ? d : best[k];
            bi[k]   = m ? n : bi[k];
        }
    }
#pragma unroll
    for (int k = 0; k < FVPT; ++k) {
        unsigned int bits = __float_as_uint(best[k]);
        unsigned int key  = bits ^ (unsigned int)(((int)bits >> 31) | 0x80000000);
        unsigned long long packed =
            ((unsigned long long)key << 32) | (unsigned int)(ns * NL + bi[k]);
        atomicMin(&mi64[(size_t)b * V_PTS + vbase + k * 256], packed);
    }
}

__global__ __launch_bounds__(256) void k_pool_at(const unsigned long long* __restrict__ mi64,
                                                 const float* __restrict__ feats,
                                                 float* __restrict__ partial) {
    __shared__ float msk[N_RES];
    __shared__ float4 red[8][32];
    const int b   = blockIdx.x >> 4;
    const int seg = blockIdx.x & (SEGS - 1);

    for (int i = threadIdx.x; i < N_RES; i += 256) msk[i] = 0.0f;
    __syncthreads();
    const unsigned long long* mb = mi64 + (size_t)b * V_PTS;
    for (int v = threadIdx.x; v < V_PTS; v += 256)
        msk[(unsigned int)mb[v]] = 1.0f;
    __syncthreads();

    const int q = threadIdx.x & 31;
    const int s = threadIdx.x >> 5;
    const int n0 = seg * (N_RES / SEGS);
    const float4* fb4 = (const float4*)(feats + ((size_t)b * N_RES + n0) * H_DIM);

    float4 acc = make_float4(0.f, 0.f, 0.f, 0.f);
#pragma unroll
    for (int n = 0; n < N_RES / SEGS / 8; ++n) {
        const int nn = s + n * 8;
        const float m = msk[n0 + nn];
        const float4 f = fb4[(size_t)nn * 32 + q];
        acc.x = fmaf(f.x, m, acc.x);
        acc.y = fmaf(f.y, m, acc.y);
        acc.z = fmaf(f.z, m, acc.z);
        acc.w = fmaf(f.w, m, acc.w);
    }
    red[s][q] = acc;
    __syncthreads();
    if (s == 0) {
        float4 t = acc;
#pragma unroll
        for (int i = 1; i < 8; ++i) {
            t.x += red[i][q].x; t.y += red[i][q].y;
            t.z += red[i][q].z; t.w += red[i][q].w;
        }
        ((float4*)partial)[((size_t)b * SEGS + seg) * 32 + q] = t;
    }
}

// ---------------------------------------------------------------------------
// Kernel 3: per-graph pooled reduce + MLP. 16 blocks x 128 threads.
// ---------------------------------------------------------------------------
__global__ __launch_bounds__(128) void k_mlp(const float* __restrict__ partial,
                                             const float* __restrict__ W1,
                                             const float* __restrict__ b1,
                                             const float* __restrict__ W2,
                                             const float* __restrict__ b2,
                                             float* __restrict__ out) {
    __shared__ float pooled[H_DIM];
    __shared__ float h1[H_DIM];
    const int b = blockIdx.x;
    const int j = threadIdx.x;

    float s = 0.0f;
#pragma unroll
    for (int g = 0; g < SEGS; ++g)
        s += partial[((size_t)b * SEGS + g) * H_DIM + j];
    pooled[j] = s;
    __syncthreads();

    float acc = b1[j];
#pragma unroll 8
    for (int hh = 0; hh < H_DIM; ++hh)
        acc = fmaf(pooled[hh], W1[hh * H_DIM + j], acc);
    h1[j] = fmaxf(acc, 0.0f);
    __syncthreads();

    if (j < C_OUT) {
        float o = b2[j];
#pragma unroll 8
        for (int hh = 0; hh < H_DIM; ++hh)
            o = fmaf(h1[hh], W2[hh * C_OUT + j], o);
        out[(size_t)b * C_OUT + j] = o;
    }
}

extern "C" void kernel_launch(void* const* d_in, const int* in_sizes, int n_in,
                              void* d_out, int out_size, void* d_ws, size_t ws_size,
                              hipStream_t stream) {
    const float* verts  = (const float*)d_in[0];   // [B,V,3]
    const float* coords = (const float*)d_in[1];   // [B,N,3]
    const float* feats  = (const float*)d_in[2];   // [B,N,H]
    const float* W1     = (const float*)d_in[3];   // [H,H]
    const float* b1     = (const float*)d_in[4];   // [H]
    const float* W2     = (const float*)d_in[5];   // [H,C_OUT]
    const float* b2     = (const float*)d_in[6];   // [C_OUT]
    float* out = (float*)d_out;                    // [B,C_OUT]

    // workspace layout (~4.6 MB)
    const size_t vf4_bytes  = (size_t)B_GR * V_PTS * 16;       // 2 MB
    const size_t sf4_bytes  = (size_t)B_GR * N_RES * 16;       // 512 KB
    const size_t sidx_bytes = (size_t)B_GR * N_RES * 4;        // 128 KB
    const size_t cell_bytes = (size_t)B_GR * CPAD * 4;         // ~33 KB
    const size_t msk_bytes  = (size_t)B_GR * N_RES * 4;        // 128 KB
    const size_t pp_bytes   = (size_t)B_GR * SEGS * H_DIM * 4; // 128 KB
    const size_t mi_bytes   = (size_t)B_GR * V_PTS * 8;        // 1 MB
    const size_t list_bytes = (size_t)B_GR * V_PTS * 4;        // 512 KB
    const size_t cnt_bytes  = 256;
    const size_t hist_bytes = (size_t)B_GR * NB * 4;           // 32 KB each
    const size_t need = vf4_bytes + sf4_bytes + sidx_bytes + cell_bytes +
                        msk_bytes + pp_bytes + mi_bytes + list_bytes + cnt_bytes +
                        4 * hist_bytes;

    if (ws_size >= need) {
        char* p = (char*)d_ws;
        float4*             vf4g  = (float4*)p;             p += vf4_bytes;
        float4*             sf4g  = (float4*)p;             p += sf4_bytes;
        unsigned int*       sidxg = (unsigned int*)p;       p += sidx_bytes;
        unsigned int*       cells = (unsigned int*)p;       p += cell_bytes;
        float*              msk   = (float*)p;              p += msk_bytes;
        float*              partial = (float*)p;            p += pp_bytes;
        unsigned long long* mi64  = (unsigned long long*)p; p += mi_bytes;
        unsigned int*       list  = (unsigned int*)p;       p += list_bytes;
        unsigned int*       cnt   = (unsigned int*)p;       p += cnt_bytes;
        unsigned int*       histR = (unsigned int*)p;       p += hist_bytes;
        unsigned int*       histV = (unsigned int*)p;       p += hist_bytes;
        unsigned int*       cursR = (unsigned int*)p;       p += hist_bytes;
        unsigned int*       cursV = (unsigned int*)p;

        hipMemsetAsync(histR, 0, 2 * hist_bytes, stream);   // histR+histV adjacent
        hipMemsetAsync(mi64, 0xFF, mi_bytes, stream);
        k_hist    <<<B_GR * 16,              256, 0, stream>>>(coords, verts, histR, histV,
                                                               msk, cnt);
        k_scan    <<<B_GR,                   256, 0, stream>>>(histR, histV, cells,
                                                               cursR, cursV);
        k_scatter <<<B_GR * 16,              256, 0, stream>>>(coords, verts, sf4g, sidxg,
                                                               vf4g, cursR, cursV);
        k_search  <<<B_GR * 16 * S_CHK,      256, 0, stream>>>(vf4g, sf4g, sidxg, cells, mi64);
        k_finalize<<<B_GR * V_PTS / 256,     256, 0, stream>>>(mi64, msk, list, cnt);
        k_fallback<<<2048,                   256, 0, stream>>>(vf4g, sf4g, sidxg, cells,
                                                               mi64, list, cnt, msk);
        k_pool_m  <<<B_GR * SEGS,            256, 0, stream>>>(msk, feats, partial);
        k_mlp     <<<B_GR,                   128, 0, stream>>>(partial, W1, b1, W2, b2, out);
    } else {
        // ---- fallback: brute-force atomicMin path ----
        unsigned long long* mi64 = (unsigned long long*)d_ws;              // 1 MB
        float* partial = (float*)((char*)d_ws + (size_t)B_GR * V_PTS * 8); // 128 KB

        hipMemsetAsync(mi64, 0xFF, (size_t)B_GR * V_PTS * 8, stream);
        k_argmin_at<<<B_GR * FVBLKS * NSPLIT, 256, 0, stream>>>(verts, coords, mi64);
        k_pool_at  <<<B_GR * SEGS,            256, 0, stream>>>(mi64, feats, partial);
        k_mlp      <<<B_GR,                   128, 0, stream>>>(partial, W1, b1, W2, b2, out);
    }
}